// Round 4
// baseline (107.814 us; speedup 1.0000x reference)
//
#include <hip/hip_runtime.h>

// Problem constants (from reference)
constexpr int B = 16384;
constexpr int S = 4;
constexpr int L = 16;
constexpr int D = 256;           // 256 floats per row = 64 lanes x float4
constexpr int BOS_ID = 98;
constexpr int N_CHAR = 58;

typedef float vfloat4 __attribute__((ext_vector_type(4)));

// v5: LDS-stage char_table (59.4 KB) once per block — the last untested
// bottleneck candidate. Every prior version gathered char rows from L2
// (~200-900 cy latency, vmcnt-waited before the masked fma). ds_read_b128
// from LDS is ~120 cy, pipelined, conflict-free for a wave's 1 KB
// contiguous row read. 1024-thread blocks: 59.4 KB LDS -> 2 blocks/CU ->
// 32 waves/CU resident; __launch_bounds__(1024,8) caps VGPR at 64.
// The staging is a bitwise copy and accumulation order is unchanged
// (masked fma, ascending l), so output is bit-identical to v4.
__global__ __launch_bounds__(1024, 8) void actions_emb_lds(
    const int*   __restrict__ char_ids,     // (B,S,L) = (B,64)
    const int*   __restrict__ char_len,     // (B,S)
    const int*   __restrict__ action_ids,   // (B,S)
    const int*   __restrict__ slot_type,    // (B,S)
    const float* __restrict__ char_table,   // (58,D)
    const float* __restrict__ action_table, // (99,D)
    float*       __restrict__ out)          // (B,S+1,D)
{
    __shared__ float tbl[N_CHAR * D];       // 59392 B

    const int tid = threadIdx.x;

    // ---- stage char_table -> LDS (vector copy, 4 rounds of 1024 float4) ----
    {
        const vfloat4* __restrict__ src = reinterpret_cast<const vfloat4*>(char_table);
        vfloat4*                    dst = reinterpret_cast<vfloat4*>(tbl);
        #pragma unroll
        for (int k = 0; k < 4; ++k) {
            const int i = tid + k * 1024;
            if (i < N_CHAR * D / 4) dst[i] = src[i];
        }
    }
    __syncthreads();

    const int lane = tid & 63;
    // one wave per batch element; readfirstlane makes b provably uniform
    const int b = __builtin_amdgcn_readfirstlane(
        (int)((blockIdx.x * blockDim.x + threadIdx.x) >> 6));

    // Wave-uniform control loads.
    const int4 st4 = *reinterpret_cast<const int4*>(slot_type  + b * S);
    const int4 cl4 = *reinterpret_cast<const int4*>(char_len   + b * S);
    const int4 ai4 = *reinterpret_cast<const int4*>(action_ids + b * S);

    const vfloat4 bos =
        *(reinterpret_cast<const vfloat4*>(action_table + BOS_ID * D) + lane);

    vfloat4* outv = reinterpret_cast<vfloat4*>(out + (size_t)b * 5 * D) + lane;
    outv[0] = bos;                                  // BOS row (plain store)

    #pragma unroll
    for (int s = 0; s < S; ++s) {
        const int t   = __builtin_amdgcn_readfirstlane(
            (s == 0) ? st4.x : (s == 1) ? st4.y : (s == 2) ? st4.z : st4.w);
        const int len = __builtin_amdgcn_readfirstlane(
            (s == 0) ? cl4.x : (s == 1) ? cl4.y : (s == 2) ? cl4.z : cl4.w);
        const int aid = __builtin_amdgcn_readfirstlane(
            (s == 0) ? ai4.x : (s == 1) ? ai4.y : (s == 2) ? ai4.z : ai4.w);

        vfloat4 r = {0.f, 0.f, 0.f, 0.f};

        if (t == 1) {
            r = *(reinterpret_cast<const vfloat4*>(action_table + aid * D) + lane);
        } else if (t == 0) {
            // 16 wave-uniform char ids for this slot -> SGPRs.
            const int* __restrict__ idp = char_ids + b * (S * L) + s * L;
            int id[L];
            #pragma unroll
            for (int l = 0; l < L; ++l)
                id[l] = __builtin_amdgcn_readfirstlane(idp[l]);

            // Groups of 4 LDS gathers; group guard is wave-uniform,
            // per-element {0,1} masks keep the sum bit-exact
            // (fma(1,e,r)==r+e, fma(0,e,r)==r in f32, ascending l order).
            #pragma unroll
            for (int g = 0; g < 4; ++g) {
                if (len > 4 * g) {
                    const vfloat4 e0 = *(reinterpret_cast<const vfloat4*>(
                                             tbl + id[4 * g + 0] * D) + lane);
                    const vfloat4 e1 = *(reinterpret_cast<const vfloat4*>(
                                             tbl + id[4 * g + 1] * D) + lane);
                    const vfloat4 e2 = *(reinterpret_cast<const vfloat4*>(
                                             tbl + id[4 * g + 2] * D) + lane);
                    const vfloat4 e3 = *(reinterpret_cast<const vfloat4*>(
                                             tbl + id[4 * g + 3] * D) + lane);
                    const float m0 = (4 * g + 0 < len) ? 1.0f : 0.0f;
                    const float m1 = (4 * g + 1 < len) ? 1.0f : 0.0f;
                    const float m2 = (4 * g + 2 < len) ? 1.0f : 0.0f;
                    const float m3 = (4 * g + 3 < len) ? 1.0f : 0.0f;
                    r += m0 * e0;
                    r += m1 * e1;
                    r += m2 * e2;
                    r += m3 * e3;
                }
            }
            const float flen = (float)len;
            r /= flen;                         // exact f32 div, matches ref
        }
        // t == 2: zeros

        outv[(s + 1) * (D / 4)] = r;           // plain store
    }
}

extern "C" void kernel_launch(void* const* d_in, const int* in_sizes, int n_in,
                              void* d_out, int out_size, void* d_ws, size_t ws_size,
                              hipStream_t stream) {
    const int*   char_ids     = (const int*)  d_in[0];
    const int*   char_len     = (const int*)  d_in[1];
    const int*   action_ids   = (const int*)  d_in[2];
    const int*   slot_type    = (const int*)  d_in[3];
    const float* char_table   = (const float*)d_in[4];
    const float* action_table = (const float*)d_in[5];
    float*       out          = (float*)      d_out;

    // 1024-thread blocks, 16 waves/block, one element/wave: 1024 blocks.
    const int blocks = B / 16;
    actions_emb_lds<<<blocks, 1024, 0, stream>>>(
        char_ids, char_len, action_ids, slot_type, char_table, action_table, out);
}